// Round 17
// baseline (108.125 us; speedup 1.0000x reference)
//
#include <hip/hip_runtime.h>

#define BATCH  512
#define K_OPS  16
#define D2     128
#define TSTEPS 64

#define TAYB   256                // taylor blocks in K1
#define ZK1    1120               // K1 zero blocks: 16 full slabs -> batches 0..279
#define CHAINB 512                // K2 chains (interleaved at bid%4==0, bid<2048)
#define K2GRID 2368               // 512 chains + 1856 zeros (batches 280..511)

typedef float vf4 __attribute__((ext_vector_type(4)));

#define ASM_BAR() asm volatile("s_waitcnt lgkmcnt(0)\n\ts_barrier" ::: "memory")

__device__ inline int argmax16(const float* __restrict__ ub) {
    float m = ub[0]; int lab = 0;
    #pragma unroll
    for (int j = 1; j < K_OPS; ++j) {
        const float v = ub[j];
        if (v > m) { m = v; lab = j; }
    }
    return lab;
}

// ---------------------------------------------------------------------------
// K0: X_k = S@sym(H_k) -> global, + labels. 16 blocks.
// ---------------------------------------------------------------------------
__global__ __launch_bounds__(256) void k_xbuild(
    const float* __restrict__ H, const float* __restrict__ u,
    float* __restrict__ X, int* __restrict__ labels)
{
    __shared__ float Hs[D2][132];
    const int k = blockIdx.x, tid = threadIdx.x;

    if (tid < 32) labels[k * 32 + tid] = argmax16(u + (k * 32 + tid) * K_OPS);

    const float* Hk = H + (size_t)k * D2 * D2;
    #pragma unroll
    for (int mm = 0; mm < 16; ++mm) {
        const int idx4 = tid + mm * 256;
        const float4 v = *(const float4*)&Hk[idx4 * 4];
        *(float4*)&Hs[idx4 >> 5][(idx4 & 31) * 4] = v;
    }
    __syncthreads();

    float* Xk = X + (size_t)k * D2 * D2;
    #pragma unroll 4
    for (int m = 0; m < 64; ++m) {
        const int idx = tid + m * 256;
        const int i = idx >> 7, j = idx & 127;
        const int i2 = i ^ 64;
        const float sgn = (i < 64) ? 0.5f : -0.5f;
        Xk[idx] = sgn * (Hs[i2][j] + Hs[j][i2]);
    }
}

// ---------------------------------------------------------------------------
// K1: blocks 0..255 = 10 Taylor orders (x in VGPR from global X, LDS 21.5 KB);
//     blocks 256.. = full-slab zero of batches 0..279 (140 MB), plain stores.
// ---------------------------------------------------------------------------
__global__ __launch_bounds__(256, 2) void k_taylor(
    const float* __restrict__ X, float* __restrict__ ACC,
    float* __restrict__ out)
{
    const int bid = blockIdx.x, tid = threadIdx.x;

    if (bid >= TAYB) {
        const int zb = bid - TAYB;
        const vf4 zv = {0.f, 0.f, 0.f, 0.f};
        vf4* base = (vf4*)(out + (size_t)zb * 16 * 2048);
        #pragma unroll 4
        for (int s = 0; s < 16; ++s) {
            vf4* p = base + (size_t)s * 512;
            p[tid]       = zv;
            p[tid + 256] = zv;
        }
        return;
    }

    __shared__ float PsT[D2][12];
    __shared__ float Red[3][64][20];

    const int k   = bid >> 4;
    const int r0s = (bid & 15) * 8;
    const float* Xk = X + (size_t)k * D2 * D2;

    const int jg = tid >> 6;
    const int rg = (tid >> 5) & 1;
    const int cg = tid & 31;

    float x[32][4];
    #pragma unroll
    for (int m = 0; m < 32; ++m) {
        const int j = (m << 2) | jg;
        const float4 a = *(const float4*)&Xk[j * D2 + cg * 4];
        x[m][0] = a.x; x[m][1] = a.y; x[m][2] = a.z; x[m][3] = a.w;
    }

    {
        const int c = tid & 127, rh = tid >> 7;
        float4 v; float* vp = (float*)&v;
        #pragma unroll
        for (int rr = 0; rr < 4; ++rr)
            vp[rr] = Xk[(r0s + rh * 4 + rr) * D2 + c];
        *(float4*)&PsT[c][rh * 4] = v;
    }

    float acc[4][4];
    if (jg == 0) {
        #pragma unroll
        for (int rr = 0; rr < 4; ++rr) {
            const int row = r0s + rg * 4 + rr;
            const float4 a = *(const float4*)&Xk[row * D2 + cg * 4];
            acc[rr][0] = a.x + ((row == cg * 4 + 0) ? 1.0f : 0.0f);
            acc[rr][1] = a.y + ((row == cg * 4 + 1) ? 1.0f : 0.0f);
            acc[rr][2] = a.z + ((row == cg * 4 + 2) ? 1.0f : 0.0f);
            acc[rr][3] = a.w + ((row == cg * 4 + 3) ? 1.0f : 0.0f);
        }
    }
    __syncthreads();

    for (int it = 2; it <= 10; ++it) {
        float nv[4][4] = {{0.f,0.f,0.f,0.f},{0.f,0.f,0.f,0.f},
                          {0.f,0.f,0.f,0.f},{0.f,0.f,0.f,0.f}};
        #pragma unroll
        for (int m = 0; m < 32; ++m) {
            const int j = (m << 2) | jg;
            const float4 pv = *(const float4*)&PsT[j][rg * 4];
            const float p[4] = {pv.x, pv.y, pv.z, pv.w};
            #pragma unroll
            for (int rr = 0; rr < 4; ++rr)
                #pragma unroll
                for (int cc = 0; cc < 4; ++cc)
                    nv[rr][cc] = fmaf(p[rr], x[m][cc], nv[rr][cc]);
        }
        if (jg != 0) {
            float* rb = Red[jg - 1][rg * 32 + cg];
            #pragma unroll
            for (int rr = 0; rr < 4; ++rr)
                *(float4*)&rb[rr * 4] =
                    make_float4(nv[rr][0], nv[rr][1], nv[rr][2], nv[rr][3]);
        }
        __syncthreads();
        if (jg == 0) {
            #pragma unroll
            for (int g = 0; g < 3; ++g) {
                const float* rb = Red[g][rg * 32 + cg];
                #pragma unroll
                for (int rr = 0; rr < 4; ++rr) {
                    const float4 p = *(const float4*)&rb[rr * 4];
                    nv[rr][0] += p.x; nv[rr][1] += p.y;
                    nv[rr][2] += p.z; nv[rr][3] += p.w;
                }
            }
            const float inv = 1.0f / (float)it;
            #pragma unroll
            for (int rr = 0; rr < 4; ++rr)
                #pragma unroll
                for (int cc = 0; cc < 4; ++cc) {
                    nv[rr][cc] *= inv;
                    acc[rr][cc] += nv[rr][cc];
                }
            #pragma unroll
            for (int cc = 0; cc < 4; ++cc)
                *(float4*)&PsT[cg * 4 + cc][rg * 4] =
                    make_float4(nv[0][cc], nv[1][cc], nv[2][cc], nv[3][cc]);
        }
        __syncthreads();
    }

    if (jg == 0) {
        float* Ak = ACC + ((size_t)k * D2 + r0s + rg * 4) * D2;
        #pragma unroll
        for (int rr = 0; rr < 4; ++rr)
            *(float4*)&Ak[rr * D2 + cg * 4] =
                make_float4(acc[rr][0], acc[rr][1], acc[rr][2], acc[rr][3]);
    }
}

// ---------------------------------------------------------------------------
// K2: chains INTERLEAVED with zero blocks via bid mapping so every CU
//     co-runs chain compute + zero stores from t=0.
//       bid < 2048 && bid%4==0 -> chain c = bid>>2   (512 chains)
//       else                   -> zero  z            (1856 blocks,
//                                  batches 280..511, 8 slabs, label-skip)
//     Chain: 4-wave column split (R16-proven), 2 lgkm-only barriers/step.
// ---------------------------------------------------------------------------
__global__ __launch_bounds__(256, 2) void k_prop(
    const float* __restrict__ s_in, const float* __restrict__ ACC,
    const int* __restrict__ labels, float* __restrict__ out)
{
    const int bid = blockIdx.x, tid = threadIdx.x;

    const bool is_chain = (bid < 2048) && ((bid & 3) == 0);

    if (!is_chain) {
        // zero ordinal: bids 1,2,3,5,6,7,... (skip bid%4==0 below 2048)
        const int z = (bid < 2048) ? (bid - (bid + 3) / 4)
                                   : (1536 + (bid - 2048));
        const int b = 280 + (z >> 3);
        const int sub = z & 7;                 // 8 slabs each
        const int lab = labels[b];
        const vf4 zv = {0.f, 0.f, 0.f, 0.f};
        vf4* base = (vf4*)(out + ((size_t)b * TSTEPS + sub * 8) * (K_OPS * D2));
        #pragma unroll 4
        for (int s = 0; s < 8; ++s) {
            vf4* p = base + (size_t)s * 512;
            #pragma unroll
            for (int q = 0; q < 2; ++q) {
                const int slot = tid + q * 256;
                if ((slot >> 5) != lab) p[slot] = zv;
            }
        }
        return;
    }

    __shared__ float sbuf[D2];       // current state
    __shared__ float part[4][132];   // per-wave partials, padded

    const int q = tid >> 6;          // wave: column quarter
    const int l = tid & 63;
    const int b = bid >> 2;          // chain batch
    const int lab = labels[b];

    // lane l of wave q: rows l and l+64, columns [32q, 32q+32)
    float rA[32], rB[32];
    {
        const float4* pl = (const float4*)(ACC + ((size_t)lab * D2 + l) * D2 + q * 32);
        const float4* ph = (const float4*)(ACC + ((size_t)lab * D2 + l + 64) * D2 + q * 32);
        #pragma unroll
        for (int m = 0; m < 8; ++m) {
            const float4 a = pl[m];
            rA[4*m+0] = a.x; rA[4*m+1] = a.y; rA[4*m+2] = a.z; rA[4*m+3] = a.w;
            const float4 c = ph[m];
            rB[4*m+0] = c.x; rB[4*m+1] = c.y; rB[4*m+2] = c.z; rB[4*m+3] = c.w;
        }
    }

    float* ob = out + ((size_t)b * TSTEPS * K_OPS + lab) * D2;
    if (tid < D2) {
        const float s0 = s_in[((size_t)b * K_OPS + lab) * D2 + tid];
        sbuf[tid] = s0;
        ob[tid] = s0;                            // t = 0
    }
    ASM_BAR();

    for (int t = 1; t < TSTEPS; ++t) {
        float p0 = 0.f, p1 = 0.f;
        const float4* s4 = (const float4*)&sbuf[q * 32];
        #pragma unroll
        for (int m = 0; m < 8; ++m) {
            const float4 sv = s4[m];             // broadcast (uniform addr)
            p0 = fmaf(rA[4*m+0], sv.x, p0);
            p0 = fmaf(rA[4*m+1], sv.y, p0);
            p0 = fmaf(rA[4*m+2], sv.z, p0);
            p0 = fmaf(rA[4*m+3], sv.w, p0);
            p1 = fmaf(rB[4*m+0], sv.x, p1);
            p1 = fmaf(rB[4*m+1], sv.y, p1);
            p1 = fmaf(rB[4*m+2], sv.z, p1);
            p1 = fmaf(rB[4*m+3], sv.w, p1);
        }
        part[q][l]      = p0;
        part[q][64 + l] = p1;
        ASM_BAR();
        if (q < 2) {
            const int r = q * 64 + l;            // rows 0..127
            const float y = part[0][r] + part[1][r] + part[2][r] + part[3][r];
            sbuf[r] = y;
            ob[(size_t)t * (K_OPS * D2) + r] = y;
        }
        ASM_BAR();
    }
}

extern "C" void kernel_launch(void* const* d_in, const int* in_sizes, int n_in,
                              void* d_out, int out_size, void* d_ws, size_t ws_size,
                              hipStream_t stream) {
    const float* u_t = (const float*)d_in[0];   // [512,16]
    const float* s_t = (const float*)d_in[1];   // [512,16,128]
    const float* H   = (const float*)d_in[2];   // [16,128,128]

    float* out    = (float*)d_out;
    float* Xw     = (float*)d_ws;                       // [16,128,128] = 1 MB
    float* Aw     = Xw + K_OPS * D2 * D2;               // [16,128,128] = 1 MB
    int*   labels = (int*)(Aw + K_OPS * D2 * D2);       // [512]

    hipLaunchKernelGGL(k_xbuild, dim3(K_OPS), dim3(256), 0, stream,
                       H, u_t, Xw, labels);
    hipLaunchKernelGGL(k_taylor, dim3(TAYB + ZK1), dim3(256), 0, stream,
                       Xw, Aw, out);
    hipLaunchKernelGGL(k_prop, dim3(K2GRID), dim3(256), 0, stream,
                       s_t, Aw, labels, out);
}

// Round 18
// 61.330 us; speedup vs baseline: 1.7630x; 1.7630x over previous
//
#include <hip/hip_runtime.h>

#define BATCH  512
#define K_OPS  16
#define D2     128
#define TSTEPS 64

#define TAYB   256                // taylor blocks in K1
#define ZK1    1056               // K1 zero blocks: 16 full slabs -> batches 0..263
#define CHAINB 512                // K2 chain blocks (bids 0..511: all co-resident gen-1)
#define ZK2    1984               // K2 zero blocks: batches 264..511, 8 slabs each

typedef float vf4 __attribute__((ext_vector_type(4)));

#define ASM_BAR() asm volatile("s_waitcnt lgkmcnt(0)\n\ts_barrier" ::: "memory")

__device__ inline int argmax16(const float* __restrict__ ub) {
    float m = ub[0]; int lab = 0;
    #pragma unroll
    for (int j = 1; j < K_OPS; ++j) {
        const float v = ub[j];
        if (v > m) { m = v; lab = j; }
    }
    return lab;
}

// ---------------------------------------------------------------------------
// K0: X_k = S@sym(H_k) -> global, + labels. 16 blocks.
// ---------------------------------------------------------------------------
__global__ __launch_bounds__(256) void k_xbuild(
    const float* __restrict__ H, const float* __restrict__ u,
    float* __restrict__ X, int* __restrict__ labels)
{
    __shared__ float Hs[D2][132];
    const int k = blockIdx.x, tid = threadIdx.x;

    if (tid < 32) labels[k * 32 + tid] = argmax16(u + (k * 32 + tid) * K_OPS);

    const float* Hk = H + (size_t)k * D2 * D2;
    #pragma unroll
    for (int mm = 0; mm < 16; ++mm) {
        const int idx4 = tid + mm * 256;
        const float4 v = *(const float4*)&Hk[idx4 * 4];
        *(float4*)&Hs[idx4 >> 5][(idx4 & 31) * 4] = v;
    }
    __syncthreads();

    float* Xk = X + (size_t)k * D2 * D2;
    #pragma unroll 4
    for (int m = 0; m < 64; ++m) {
        const int idx = tid + m * 256;
        const int i = idx >> 7, j = idx & 127;
        const int i2 = i ^ 64;
        const float sgn = (i < 64) ? 0.5f : -0.5f;
        Xk[idx] = sgn * (Hs[i2][j] + Hs[j][i2]);
    }
}

// ---------------------------------------------------------------------------
// K1: blocks 0..255 = 10 Taylor orders (x in VGPR from global X, LDS 21.5 KB);
//     blocks 256.. = full-slab zero of batches 0..263 (132 MB), plain stores.
// ---------------------------------------------------------------------------
__global__ __launch_bounds__(256, 2) void k_taylor(
    const float* __restrict__ X, float* __restrict__ ACC,
    float* __restrict__ out)
{
    const int bid = blockIdx.x, tid = threadIdx.x;

    if (bid >= TAYB) {
        const int zb = bid - TAYB;
        const vf4 zv = {0.f, 0.f, 0.f, 0.f};
        vf4* base = (vf4*)(out + (size_t)zb * 16 * 2048);
        #pragma unroll 4
        for (int s = 0; s < 16; ++s) {
            vf4* p = base + (size_t)s * 512;
            p[tid]       = zv;
            p[tid + 256] = zv;
        }
        return;
    }

    __shared__ float PsT[D2][12];
    __shared__ float Red[3][64][20];

    const int k   = bid >> 4;
    const int r0s = (bid & 15) * 8;
    const float* Xk = X + (size_t)k * D2 * D2;

    const int jg = tid >> 6;
    const int rg = (tid >> 5) & 1;
    const int cg = tid & 31;

    float x[32][4];
    #pragma unroll
    for (int m = 0; m < 32; ++m) {
        const int j = (m << 2) | jg;
        const float4 a = *(const float4*)&Xk[j * D2 + cg * 4];
        x[m][0] = a.x; x[m][1] = a.y; x[m][2] = a.z; x[m][3] = a.w;
    }

    {
        const int c = tid & 127, rh = tid >> 7;
        float4 v; float* vp = (float*)&v;
        #pragma unroll
        for (int rr = 0; rr < 4; ++rr)
            vp[rr] = Xk[(r0s + rh * 4 + rr) * D2 + c];
        *(float4*)&PsT[c][rh * 4] = v;
    }

    float acc[4][4];
    if (jg == 0) {
        #pragma unroll
        for (int rr = 0; rr < 4; ++rr) {
            const int row = r0s + rg * 4 + rr;
            const float4 a = *(const float4*)&Xk[row * D2 + cg * 4];
            acc[rr][0] = a.x + ((row == cg * 4 + 0) ? 1.0f : 0.0f);
            acc[rr][1] = a.y + ((row == cg * 4 + 1) ? 1.0f : 0.0f);
            acc[rr][2] = a.z + ((row == cg * 4 + 2) ? 1.0f : 0.0f);
            acc[rr][3] = a.w + ((row == cg * 4 + 3) ? 1.0f : 0.0f);
        }
    }
    __syncthreads();

    for (int it = 2; it <= 10; ++it) {
        float nv[4][4] = {{0.f,0.f,0.f,0.f},{0.f,0.f,0.f,0.f},
                          {0.f,0.f,0.f,0.f},{0.f,0.f,0.f,0.f}};
        #pragma unroll
        for (int m = 0; m < 32; ++m) {
            const int j = (m << 2) | jg;
            const float4 pv = *(const float4*)&PsT[j][rg * 4];
            const float p[4] = {pv.x, pv.y, pv.z, pv.w};
            #pragma unroll
            for (int rr = 0; rr < 4; ++rr)
                #pragma unroll
                for (int cc = 0; cc < 4; ++cc)
                    nv[rr][cc] = fmaf(p[rr], x[m][cc], nv[rr][cc]);
        }
        if (jg != 0) {
            float* rb = Red[jg - 1][rg * 32 + cg];
            #pragma unroll
            for (int rr = 0; rr < 4; ++rr)
                *(float4*)&rb[rr * 4] =
                    make_float4(nv[rr][0], nv[rr][1], nv[rr][2], nv[rr][3]);
        }
        __syncthreads();
        if (jg == 0) {
            #pragma unroll
            for (int g = 0; g < 3; ++g) {
                const float* rb = Red[g][rg * 32 + cg];
                #pragma unroll
                for (int rr = 0; rr < 4; ++rr) {
                    const float4 p = *(const float4*)&rb[rr * 4];
                    nv[rr][0] += p.x; nv[rr][1] += p.y;
                    nv[rr][2] += p.z; nv[rr][3] += p.w;
                }
            }
            const float inv = 1.0f / (float)it;
            #pragma unroll
            for (int rr = 0; rr < 4; ++rr)
                #pragma unroll
                for (int cc = 0; cc < 4; ++cc) {
                    nv[rr][cc] *= inv;
                    acc[rr][cc] += nv[rr][cc];
                }
            #pragma unroll
            for (int cc = 0; cc < 4; ++cc)
                *(float4*)&PsT[cg * 4 + cc][rg * 4] =
                    make_float4(nv[0][cc], nv[1][cc], nv[2][cc], nv[3][cc]);
        }
        __syncthreads();
    }

    if (jg == 0) {
        float* Ak = ACC + ((size_t)k * D2 + r0s + rg * 4) * D2;
        #pragma unroll
        for (int rr = 0; rr < 4; ++rr)
            *(float4*)&Ak[rr * D2 + cg * 4] =
                make_float4(acc[rr][0], acc[rr][1], acc[rr][2], acc[rr][3]);
    }
}

// ---------------------------------------------------------------------------
// K2: blocks 0..511 = chains (4-wave column split, R16-proven), with the
//     full trajectory buffered in out_lds (32 KB) so chain waves issue NO
//     global stores during the zero-saturated window; bulk store at end.
//     blocks 512.. = label-skip zeros, batches 264..511 (8 slabs each).
// ---------------------------------------------------------------------------
__global__ __launch_bounds__(256, 2) void k_prop(
    const float* __restrict__ s_in, const float* __restrict__ ACC,
    const int* __restrict__ labels, float* __restrict__ out)
{
    const int bid = blockIdx.x, tid = threadIdx.x;

    if (bid >= CHAINB) {
        const int z = bid - CHAINB;            // 0..1983
        const int b = 264 + (z >> 3);
        const int sub = z & 7;                 // 8 slabs each
        const int lab = labels[b];
        const vf4 zv = {0.f, 0.f, 0.f, 0.f};
        vf4* base = (vf4*)(out + ((size_t)b * TSTEPS + sub * 8) * (K_OPS * D2));
        #pragma unroll 4
        for (int s = 0; s < 8; ++s) {
            vf4* p = base + (size_t)s * 512;
            #pragma unroll
            for (int q = 0; q < 2; ++q) {
                const int slot = tid + q * 256;
                if ((slot >> 5) != lab) p[slot] = zv;
            }
        }
        return;
    }

    __shared__ float sbuf[D2];            // current state
    __shared__ float part[4][132];        // per-wave partials, padded
    __shared__ float out_lds[TSTEPS][D2]; // 32 KB trajectory

    const int q = tid >> 6;          // wave: column quarter
    const int l = tid & 63;
    const int b = bid;
    const int lab = labels[b];

    // lane l of wave q: rows l and l+64, columns [32q, 32q+32)
    float rA[32], rB[32];
    {
        const float4* pl = (const float4*)(ACC + ((size_t)lab * D2 + l) * D2 + q * 32);
        const float4* ph = (const float4*)(ACC + ((size_t)lab * D2 + l + 64) * D2 + q * 32);
        #pragma unroll
        for (int m = 0; m < 8; ++m) {
            const float4 a = pl[m];
            rA[4*m+0] = a.x; rA[4*m+1] = a.y; rA[4*m+2] = a.z; rA[4*m+3] = a.w;
            const float4 c = ph[m];
            rB[4*m+0] = c.x; rB[4*m+1] = c.y; rB[4*m+2] = c.z; rB[4*m+3] = c.w;
        }
    }

    if (tid < D2) {
        const float s0 = s_in[((size_t)b * K_OPS + lab) * D2 + tid];
        sbuf[tid] = s0;
        out_lds[0][tid] = s0;
    }
    ASM_BAR();

    for (int t = 1; t < TSTEPS; ++t) {
        float p0 = 0.f, p1 = 0.f;
        const float4* s4 = (const float4*)&sbuf[q * 32];
        #pragma unroll
        for (int m = 0; m < 8; ++m) {
            const float4 sv = s4[m];             // broadcast (uniform addr)
            p0 = fmaf(rA[4*m+0], sv.x, p0);
            p0 = fmaf(rA[4*m+1], sv.y, p0);
            p0 = fmaf(rA[4*m+2], sv.z, p0);
            p0 = fmaf(rA[4*m+3], sv.w, p0);
            p1 = fmaf(rB[4*m+0], sv.x, p1);
            p1 = fmaf(rB[4*m+1], sv.y, p1);
            p1 = fmaf(rB[4*m+2], sv.z, p1);
            p1 = fmaf(rB[4*m+3], sv.w, p1);
        }
        part[q][l]      = p0;
        part[q][64 + l] = p1;
        ASM_BAR();
        if (q < 2) {
            const int r = q * 64 + l;            // rows 0..127
            const float y = part[0][r] + part[1][r] + part[2][r] + part[3][r];
            sbuf[r] = y;
            out_lds[t][r] = y;
        }
        ASM_BAR();
    }

    // ---- bulk store: 32 KB coalesced (16 MB total across all chains) ----
    const float* ol = &out_lds[0][0];
    float* ob = out + ((size_t)b * TSTEPS * K_OPS + lab) * D2;
    #pragma unroll
    for (int m = 0; m < 8; ++m) {
        const int s  = tid + m * 256;        // 0..2047 float4 slots
        const int t  = s >> 5;
        const int c4 = s & 31;
        const vf4 v = *(const vf4*)(ol + s * 4);
        ((vf4*)(ob + (size_t)t * K_OPS * D2))[c4] = v;
    }
}

extern "C" void kernel_launch(void* const* d_in, const int* in_sizes, int n_in,
                              void* d_out, int out_size, void* d_ws, size_t ws_size,
                              hipStream_t stream) {
    const float* u_t = (const float*)d_in[0];   // [512,16]
    const float* s_t = (const float*)d_in[1];   // [512,16,128]
    const float* H   = (const float*)d_in[2];   // [16,128,128]

    float* out    = (float*)d_out;
    float* Xw     = (float*)d_ws;                       // [16,128,128] = 1 MB
    float* Aw     = Xw + K_OPS * D2 * D2;               // [16,128,128] = 1 MB
    int*   labels = (int*)(Aw + K_OPS * D2 * D2);       // [512]

    hipLaunchKernelGGL(k_xbuild, dim3(K_OPS), dim3(256), 0, stream,
                       H, u_t, Xw, labels);
    hipLaunchKernelGGL(k_taylor, dim3(TAYB + ZK1), dim3(256), 0, stream,
                       Xw, Aw, out);
    hipLaunchKernelGGL(k_prop, dim3(CHAINB + ZK2), dim3(256), 0, stream,
                       s_t, Aw, labels, out);
}